// Round 3
// baseline (3676.459 us; speedup 1.0000x reference)
//
#include <hip/hip_runtime.h>
#include <math.h>

#define BSZ 512
#define NV 30
#define NT 24
#define SS 768                  // state row stride (x: 0..249, m: 250..749, pad: 750..767)
#define PL (80 * 24 * 512)      // packed ushorts per (layer, half): 80 nb-blocks x 24 kc x 512
#define NBLK 192
#define NSTEP 144

typedef __attribute__((ext_vector_type(8))) short bf16x8;
typedef __attribute__((ext_vector_type(4))) float f32x4;

__device__ __forceinline__ unsigned short f2bf(float f) {
    unsigned u = __float_as_uint(f);
    u += 0x7fffu + ((u >> 16) & 1u);        // round-to-nearest-even
    return (unsigned short)(u >> 16);
}
__device__ __forceinline__ float bf2f(unsigned short h) {
    return __uint_as_float(((unsigned)h) << 16);
}
__device__ __forceinline__ f32x4 mm(bf16x8 a, bf16x8 b, f32x4 c) {
    return __builtin_amdgcn_mfma_f32_16x16x32_bf16(a, b, c, 0, 0, 0);
}
#define LD8(p) (*(const bf16x8*)(const void*)(p))

struct RecArgs {
    const unsigned short* Pw;
    unsigned short* A0hi; unsigned short* A0lo;
    unsigned short* A1hi; unsigned short* A1lo;
    float* Sfin;
    unsigned int* cnt;
    const float* b1_sw; const float* b1_mem; const float* b1_sv;
    const float* b_sw;  const float* b_mem;  const float* b_sv;
    const float* w1_sw; const float* w1_mem; const float* w1_sv;
    const int* letters;
};

// ---------------- zero ----------------
__global__ void zero_kernel(float* p, int n) {
    int i = blockIdx.x * blockDim.x + threadIdx.x;
    int st = gridDim.x * blockDim.x;
    for (; i < n; i += st) p[i] = 0.f;
}

// ---------------- one-time weight pack: fp32 [750][N] -> hi/lo bf16 MFMA-B layout ----------------
// Phi[((nb*24 + kc)*64 + lane)*8 + j] = bf16_hi(W[kc*32 + (lane>>4)*8 + j][nb*16 + (lane&15)])
// nb 0..31 = sw (N=500 pad 512), 32..63 = mem, 64..79 = sv (N=250 pad 256). k>=750 zero-padded.
__launch_bounds__(64)
__global__ void pack_weights(const float* __restrict__ Wsw, const float* __restrict__ Wmem,
                             const float* __restrict__ Wsv,
                             unsigned short* __restrict__ Phi, unsigned short* __restrict__ Plo)
{
    const int kc = blockIdx.x;   // 0..23
    const int nb = blockIdx.y;   // 0..79
    const int l  = threadIdx.x;  // 0..63
    const int g = l >> 4, c = l & 15;
    const float* W; int N, nbl;
    if (nb < 32)      { W = Wsw;  N = 500; nbl = nb; }
    else if (nb < 64) { W = Wmem; N = 500; nbl = nb - 32; }
    else              { W = Wsv;  N = 250; nbl = nb - 64; }
    const int n = nbl * 16 + c;
    unsigned short h8[8], l8[8];
    #pragma unroll
    for (int j = 0; j < 8; ++j) {
        const int k = kc * 32 + g * 8 + j;
        const float w = (k < 750 && n < N) ? W[(size_t)k * N + n] : 0.f;
        const unsigned short h = f2bf(w);
        h8[j] = h;
        l8[j] = f2bf(w - bf2f(h));
    }
    const size_t off = ((size_t)nb * 24 + kc) * 512 + (size_t)l * 8;
    #pragma unroll
    for (int j = 0; j < 8; ++j) { Phi[off + j] = h8[j]; Plo[off + j] = l8[j]; }
}

// ---------------- persistent recurrence: all 24*6 layers in one kernel ----------------
// 192 blocks x 256 thr; 96KB LDS forces 1 block/CU and grid<=256 CUs => all resident.
// Cross-block state via agent-scope (sc1) loads/stores @ MALL; custom relaxed-atomic grid
// barrier => NO cache fences => weights stay L2-resident across all 144 layers.
// m-state carried in registers (block->cols ownership stable across layers).
__launch_bounds__(256, 1)
__global__ void recurrence(RecArgs A)
{
    __shared__ __align__(16) unsigned char lds[98304];   // [plane 0=hi,1=lo][row 0..31][1536B, XOR-swizzled]
    const int tid = threadIdx.x;
    const int bid = blockIdx.x;
    const int wv = tid >> 6;        // wave 0..3 owns col-fragment wv
    const int l6 = tid & 63;
    const int g = l6 >> 4, c = l6 & 15;
    const int asw = (c & 7) << 4;   // LDS XOR swizzle bits (row&7 == c&7 since rb*16 % 8 == 0)

    const bool svrole = (bid >= 128);
    int rt, ct;
    if (!svrole) { rt = bid >> 3; ct = bid & 7; }
    else         { const int q = bid - 128; rt = q >> 2; ct = q & 3; }
    const int m0 = rt * 32;
    const int col = ct * 64 + wv * 16 + c;

    float mreg[2][4];
    #pragma unroll
    for (int i = 0; i < 2; ++i)
        #pragma unroll
        for (int j = 0; j < 4; ++j) mreg[i][j] = 0.f;

#define FRAG(p, rb, kc) (*(const bf16x8*)(lds + (p) * 49152 + ((rb) * 16 + c) * 1536 + ((((kc) * 64) + g * 16) ^ asw)))

    #pragma unroll 1
    for (int step = 0; step < NSTEP; ++step) {
        const int t = step / 6;
        const int l = step - 6 * t;
        const unsigned short* Ahi = (step & 1) ? A.A1hi : A.A0hi;
        const unsigned short* Alo = (step & 1) ? A.A1lo : A.A0lo;
        unsigned short* Ohi = (step & 1) ? A.A0hi : A.A1hi;
        unsigned short* Olo = (step & 1) ? A.A0lo : A.A1lo;
        const unsigned short* Phi = A.Pw + (size_t)l * 2 * PL;
        const unsigned short* Plo = Phi + PL;

        // ---- stage A rows [m0, m0+32), hi+lo, into swizzled LDS (coalesced 8B agent loads) ----
        {
            unsigned long long* sh = (unsigned long long*)(Ahi + (size_t)m0 * SS);
            unsigned long long* sl = (unsigned long long*)(Alo + (size_t)m0 * SS);
            #pragma unroll 8
            for (int j = 0; j < 24; ++j) {
                const int f = tid + j * 256;          // 8B chunk id, 0..6143 (= row*192 + ko/8)
                const int row = f / 192;
                const int ko = (f - row * 192) * 8;   // byte offset within row
                const int d = row * 1536 + (ko ^ ((row & 7) << 4));
                const unsigned long long vh = __hip_atomic_load(sh + f, __ATOMIC_RELAXED, __HIP_MEMORY_SCOPE_AGENT);
                const unsigned long long vl = __hip_atomic_load(sl + f, __ATOMIC_RELAXED, __HIP_MEMORY_SCOPE_AGENT);
                *(unsigned long long*)(lds + d) = vh;
                *(unsigned long long*)(lds + 49152 + d) = vl;
            }
        }
        __syncthreads();

        f32x4 z0[2], z1[2];
        z0[0] = (f32x4)0.f; z0[1] = (f32x4)0.f;
        z1[0] = (f32x4)0.f; z1[1] = (f32x4)0.f;

        if (!svrole) {
            const size_t b0 = ((size_t)(ct * 4 + wv) * 24) * 512 + (size_t)l6 * 8;
            const size_t b1 = ((size_t)(32 + ct * 4 + wv) * 24) * 512 + (size_t)l6 * 8;
            #pragma unroll 4
            for (int kc = 0; kc < 24; ++kc) {
                const bf16x8 ah0 = FRAG(0, 0, kc), ah1 = FRAG(0, 1, kc);
                const bf16x8 al0 = FRAG(1, 0, kc), al1 = FRAG(1, 1, kc);
                bf16x8 bh = LD8(Phi + b0 + (size_t)kc * 512);
                bf16x8 bl = LD8(Plo + b0 + (size_t)kc * 512);
                z0[0] = mm(ah0, bh, z0[0]); z0[0] = mm(al0, bh, z0[0]); z0[0] = mm(ah0, bl, z0[0]);
                z0[1] = mm(ah1, bh, z0[1]); z0[1] = mm(al1, bh, z0[1]); z0[1] = mm(ah1, bl, z0[1]);
                bh = LD8(Phi + b1 + (size_t)kc * 512);
                bl = LD8(Plo + b1 + (size_t)kc * 512);
                z1[0] = mm(ah0, bh, z1[0]); z1[0] = mm(al0, bh, z1[0]); z1[0] = mm(ah0, bl, z1[0]);
                z1[1] = mm(ah1, bh, z1[1]); z1[1] = mm(al1, bh, z1[1]); z1[1] = mm(ah1, bl, z1[1]);
            }
            const float* bswp  = l ? A.b_sw  + (size_t)(l - 1) * 500 : A.b1_sw;
            const float* bmemp = l ? A.b_mem + (size_t)(l - 1) * 500 : A.b1_mem;
            if (col < 500) {
                const float bs = bswp[col];
                const float bm = bmemp[col];
                #pragma unroll
                for (int rb = 0; rb < 2; ++rb) {
                    #pragma unroll
                    for (int r = 0; r < 4; ++r) {
                        const int row = m0 + rb * 16 + g * 4 + r;
                        float zs = z0[rb][r] + bs;
                        float zm = z1[rb][r] + bm;
                        if (l == 0) {
                            const int lt = A.letters[row * NT + t];
                            zs += A.w1_sw[(size_t)(750 + lt) * 500 + col];
                            zm += A.w1_mem[(size_t)(750 + lt) * 500 + col];
                        }
                        const float s = 1.f / (1.f + expf(-zs));
                        const float mn = mreg[rb][r] * s + tanhf(zm) * (1.f - s);
                        mreg[rb][r] = mn;
                        const size_t o = (size_t)row * SS + 250 + col;
                        const unsigned short h = f2bf(mn);
                        const unsigned short lo2 = f2bf(mn - bf2f(h));
                        __hip_atomic_store(Ohi + o, h, __ATOMIC_RELAXED, __HIP_MEMORY_SCOPE_AGENT);
                        __hip_atomic_store(Olo + o, lo2, __ATOMIC_RELAXED, __HIP_MEMORY_SCOPE_AGENT);
                        if (step == NSTEP - 1) A.Sfin[o] = mn;
                    }
                }
            }
        } else {
            const size_t b0 = ((size_t)(64 + ct * 4 + wv) * 24) * 512 + (size_t)l6 * 8;
            #pragma unroll 4
            for (int kc = 0; kc < 24; ++kc) {
                const bf16x8 ah0 = FRAG(0, 0, kc), ah1 = FRAG(0, 1, kc);
                const bf16x8 al0 = FRAG(1, 0, kc), al1 = FRAG(1, 1, kc);
                const bf16x8 bh = LD8(Phi + b0 + (size_t)kc * 512);
                const bf16x8 bl = LD8(Plo + b0 + (size_t)kc * 512);
                z0[0] = mm(ah0, bh, z0[0]); z0[0] = mm(al0, bh, z0[0]); z0[0] = mm(ah0, bl, z0[0]);
                z0[1] = mm(ah1, bh, z0[1]); z0[1] = mm(al1, bh, z0[1]); z0[1] = mm(ah1, bl, z0[1]);
            }
            const float* bsvp = l ? A.b_sv + (size_t)(l - 1) * 250 : A.b1_sv;
            if (col < 250) {
                const float bv = bsvp[col];
                #pragma unroll
                for (int rb = 0; rb < 2; ++rb) {
                    #pragma unroll
                    for (int r = 0; r < 4; ++r) {
                        const int row = m0 + rb * 16 + g * 4 + r;
                        float z = z0[rb][r] + bv;
                        if (l == 0) {
                            const int lt = A.letters[row * NT + t];
                            z += A.w1_sv[(size_t)(750 + lt) * 250 + col];
                        }
                        const float x = tanhf(z);
                        const size_t o = (size_t)row * SS + col;
                        const unsigned short h = f2bf(x);
                        const unsigned short lo2 = f2bf(x - bf2f(h));
                        __hip_atomic_store(Ohi + o, h, __ATOMIC_RELAXED, __HIP_MEMORY_SCOPE_AGENT);
                        __hip_atomic_store(Olo + o, lo2, __ATOMIC_RELAXED, __HIP_MEMORY_SCOPE_AGENT);
                        if (step == NSTEP - 1) A.Sfin[o] = x;
                    }
                }
            }
        }

        // ---- fence-free grid barrier (sc1 state discipline makes relaxed atomics sufficient) ----
        __syncthreads();                         // drains vmcnt: this block's sc1 stores visible @ MALL
        if (step != NSTEP - 1) {
            if (tid == 0) {
                __hip_atomic_fetch_add(A.cnt, 1u, __ATOMIC_RELAXED, __HIP_MEMORY_SCOPE_AGENT);
                const unsigned tgt = (unsigned)NBLK * (unsigned)(step + 1);
                while (__hip_atomic_load(A.cnt, __ATOMIC_RELAXED, __HIP_MEMORY_SCOPE_AGENT) < tgt)
                    __builtin_amdgcn_s_sleep(2);
            }
            __syncthreads();
        }
    }
#undef FRAG
}

// ---------------- head GEMM: Y = tanh(X @ W + b) (fp32) ----------------
__launch_bounds__(128)
__global__ void head_gemm(const float* __restrict__ X, int ldx, int K,
                          const float* __restrict__ W, const float* __restrict__ bias,
                          float* __restrict__ Y, int N)
{
    const int tid = threadIdx.x;
    const int m0 = blockIdx.y * 32;
    const int n0 = blockIdx.x * 64;

    __shared__ float As[2][32][36];
    __shared__ float Bs[2][32][68];

    const int tx = tid & 15, ty = tid >> 4;
    const int kl = tid & 31, rl = tid >> 5;
    const int cl = tid & 63, kg = tid >> 6;
    const bool cok = (n0 + cl) < N;

    float acc[4][4] = {{0.f}};
    float ar[8], br[16];

    {
        const float* a = X + (size_t)(m0 + rl) * ldx + kl;
        #pragma unroll
        for (int i = 0; i < 8; i++) ar[i] = a[(size_t)(4 * i) * ldx];
        #pragma unroll
        for (int i = 0; i < 16; i++)
            br[i] = cok ? W[(size_t)(kg + 2 * i) * N + n0 + cl] : 0.f;
        #pragma unroll
        for (int i = 0; i < 8; i++) As[0][kl][rl + 4 * i] = ar[i];
        #pragma unroll
        for (int i = 0; i < 16; i++) Bs[0][kg + 2 * i][cl] = br[i];
    }
    __syncthreads();

    int buf = 0;
    const int NK = (K + 31) / 32;
    #pragma unroll 1
    for (int kt = 0; kt < NK; kt++) {
        const bool more = (kt + 1 < NK);
        if (more) {
            const int k0 = (kt + 1) * 32;
            const bool ka = (k0 + kl) < K;
            const float* a = X + (size_t)(m0 + rl) * ldx + k0 + kl;
            #pragma unroll
            for (int i = 0; i < 8; i++) ar[i] = ka ? a[(size_t)(4 * i) * ldx] : 0.f;
            #pragma unroll
            for (int i = 0; i < 16; i++) {
                const int kk = k0 + kg + 2 * i;
                br[i] = (cok && kk < K) ? W[(size_t)kk * N + n0 + cl] : 0.f;
            }
        }
        #pragma unroll
        for (int kk = 0; kk < 32; kk++) {
            float4 av = *(const float4*)&As[buf][kk][ty * 4];
            float4 bv = *(const float4*)&Bs[buf][kk][tx * 4];
            const float aa[4] = {av.x, av.y, av.z, av.w};
            const float bb[4] = {bv.x, bv.y, bv.z, bv.w};
            #pragma unroll
            for (int i = 0; i < 4; i++)
                #pragma unroll
                for (int j = 0; j < 4; j++)
                    acc[i][j] = fmaf(aa[i], bb[j], acc[i][j]);
        }
        if (more) {
            #pragma unroll
            for (int i = 0; i < 8; i++) As[buf ^ 1][kl][rl + 4 * i] = ar[i];
            #pragma unroll
            for (int i = 0; i < 16; i++) Bs[buf ^ 1][kg + 2 * i][cl] = br[i];
            __syncthreads();
            buf ^= 1;
        }
    }

    #pragma unroll
    for (int i = 0; i < 4; i++) {
        const int b = m0 + ty * 4 + i;
        #pragma unroll
        for (int j = 0; j < 4; j++) {
            const int n = n0 + tx * 4 + j;
            if (n < N) Y[(size_t)b * N + n] = tanhf(acc[i][j] + bias[n]);
        }
    }
}

// ---------------- final: logits (K=100, N=30) + softmax ----------------
__global__ void head_final(const float* __restrict__ Y4, const float* __restrict__ W,
                           const float* __restrict__ bias, float* __restrict__ out)
{
    const int row = blockIdx.x;
    __shared__ float y[100];
    __shared__ float z[NV];
    for (int k = threadIdx.x; k < 100; k += 64) y[k] = Y4[row * 100 + k];
    __syncthreads();
    const int n = threadIdx.x;
    if (n < NV) {
        float acc = bias[n];
        for (int k = 0; k < 100; k++) acc = fmaf(y[k], W[k * NV + n], acc);
        z[n] = acc;
    }
    __syncthreads();
    if (n < NV) {
        float mx = -1e30f;
        for (int i = 0; i < NV; i++) mx = fmaxf(mx, z[i]);
        float sum = 0.f;
        for (int i = 0; i < NV; i++) sum += expf(z[i] - mx);
        out[row * NV + n] = expf(z[n] - mx) / sum;
    }
}

extern "C" void kernel_launch(void* const* d_in, const int* in_sizes, int n_in,
                              void* d_out, int out_size, void* d_ws, size_t ws_size,
                              hipStream_t stream)
{
    const int*   letters = (const int*)  d_in[0];
    const float* w1_sv   = (const float*)d_in[1];
    const float* b1_sv   = (const float*)d_in[2];
    const float* w1_mem  = (const float*)d_in[3];
    const float* b1_mem  = (const float*)d_in[4];
    const float* w1_sw   = (const float*)d_in[5];
    const float* b1_sw   = (const float*)d_in[6];
    const float* w_sv    = (const float*)d_in[7];
    const float* b_sv    = (const float*)d_in[8];
    const float* w_mem   = (const float*)d_in[9];
    const float* b_mem   = (const float*)d_in[10];
    const float* w_sw    = (const float*)d_in[11];
    const float* b_sw    = (const float*)d_in[12];
    const float* wp1 = (const float*)d_in[13]; const float* bp1 = (const float*)d_in[14];
    const float* wp2 = (const float*)d_in[15]; const float* bp2 = (const float*)d_in[16];
    const float* wp3 = (const float*)d_in[17]; const float* bp3 = (const float*)d_in[18];
    const float* wp4 = (const float*)d_in[19]; const float* bp4 = (const float*)d_in[20];
    const float* wp5 = (const float*)d_in[21]; const float* bp5 = (const float*)d_in[22];

    // workspace layout
    float* Sfin = (float*)d_ws;                                   // BSZ*SS f32 (written at final step)
    float* cntf = Sfin + (size_t)BSZ * SS;                        // 16 f32 (barrier counter + pad)
    unsigned int* cnt = (unsigned int*)cntf;
    unsigned short* A0hi = (unsigned short*)(cntf + 16);
    unsigned short* A0lo = A0hi + (size_t)BSZ * SS;
    unsigned short* A1hi = A0lo + (size_t)BSZ * SS;
    unsigned short* A1lo = A1hi + (size_t)BSZ * SS;
    unsigned short* Pw   = A1lo + (size_t)BSZ * SS;               // 12 * PL ushorts
    float* Y1 = (float*)(Pw + (size_t)12 * PL);
    float* Y2 = Y1 + (size_t)BSZ * 450;
    float* Y3 = Y2 + (size_t)BSZ * 300;
    float* Y4 = Y3 + (size_t)BSZ * 200;

    // zero barrier counter + all 4 bf16 state planes (incl. K-pad cols, which stay 0 forever)
    zero_kernel<<<512, 256, 0, stream>>>(cntf, 16 + 2 * BSZ * SS);

    // one-time weight packing
    pack_weights<<<dim3(24, 80), 64, 0, stream>>>(w1_sw, w1_mem, w1_sv, Pw, Pw + PL);
    for (int l = 1; l < 6; ++l)
        pack_weights<<<dim3(24, 80), 64, 0, stream>>>(
            w_sw  + (size_t)(l - 1) * 750 * 500,
            w_mem + (size_t)(l - 1) * 750 * 500,
            w_sv  + (size_t)(l - 1) * 750 * 250,
            Pw + (size_t)l * 2 * PL, Pw + (size_t)l * 2 * PL + PL);

    RecArgs ra;
    ra.Pw = Pw;
    ra.A0hi = A0hi; ra.A0lo = A0lo; ra.A1hi = A1hi; ra.A1lo = A1lo;
    ra.Sfin = Sfin; ra.cnt = cnt;
    ra.b1_sw = b1_sw; ra.b1_mem = b1_mem; ra.b1_sv = b1_sv;
    ra.b_sw = b_sw;   ra.b_mem = b_mem;   ra.b_sv = b_sv;
    ra.w1_sw = w1_sw; ra.w1_mem = w1_mem; ra.w1_sv = w1_sv;
    ra.letters = letters;
    recurrence<<<NBLK, 256, 0, stream>>>(ra);

    head_gemm<<<dim3(8, 16), 128, 0, stream>>>(Sfin, SS, 750, wp1, bp1, Y1, 450);
    head_gemm<<<dim3(5, 16), 128, 0, stream>>>(Y1, 450, 450, wp2, bp2, Y2, 300);
    head_gemm<<<dim3(4, 16), 128, 0, stream>>>(Y2, 300, 300, wp3, bp3, Y3, 200);
    head_gemm<<<dim3(2, 16), 128, 0, stream>>>(Y3, 200, 200, wp4, bp4, Y4, 100);
    head_final<<<BSZ, 64, 0, stream>>>(Y4, wp5, bp5, (float*)d_out);
}

// Round 5
// 3582.927 us; speedup vs baseline: 1.0261x; 1.0261x over previous
//
#include <hip/hip_runtime.h>
#include <math.h>

#define BSZ 512
#define NV 30
#define NT 24
#define SS 768                  // state row stride (x: 0..249, m: 250..749, pad: 750..767)
#define PL (80 * 24 * 512)      // packed ushorts per (layer, half): 80 nb-blocks x 24 kc x 512
#define NBLK 48
#define NSTEP 144

typedef __attribute__((ext_vector_type(8))) short bf16x8;
typedef __attribute__((ext_vector_type(4))) float f32x4;

__device__ __forceinline__ unsigned short f2bf(float f) {
    unsigned u = __float_as_uint(f);
    u += 0x7fffu + ((u >> 16) & 1u);        // round-to-nearest-even
    return (unsigned short)(u >> 16);
}
__device__ __forceinline__ float bf2f(unsigned short h) {
    return __uint_as_float(((unsigned)h) << 16);
}
__device__ __forceinline__ f32x4 mm(bf16x8 a, bf16x8 b, f32x4 c) {
    return __builtin_amdgcn_mfma_f32_16x16x32_bf16(a, b, c, 0, 0, 0);
}
#define LD8(p) (*(const bf16x8*)(const void*)(p))

struct RecArgs {
    const unsigned short* Pw;
    unsigned short* A0hi; unsigned short* A0lo;
    unsigned short* A1hi; unsigned short* A1lo;
    float* Sfin;
    unsigned int* cnt; unsigned int* rel;
    const float* b1_sw; const float* b1_mem; const float* b1_sv;
    const float* b_sw;  const float* b_mem;  const float* b_sv;
    const float* w1_sw; const float* w1_mem; const float* w1_sv;
    const int* letters;
};

// ---------------- zero ----------------
__global__ void zero_kernel(float* p, int n) {
    int i = blockIdx.x * blockDim.x + threadIdx.x;
    int st = gridDim.x * blockDim.x;
    for (; i < n; i += st) p[i] = 0.f;
}

// ---------------- one-time weight pack: fp32 [750][N] -> hi/lo bf16 MFMA-B layout ----------------
// Phi[((nb*24 + kc)*64 + lane)*8 + j] = bf16_hi(W[kc*32 + (lane>>4)*8 + j][nb*16 + (lane&15)])
// nb 0..31 = sw (N=500 pad 512), 32..63 = mem, 64..79 = sv (N=250 pad 256). k>=750 zero-padded.
__launch_bounds__(64)
__global__ void pack_weights(const float* __restrict__ Wsw, const float* __restrict__ Wmem,
                             const float* __restrict__ Wsv,
                             unsigned short* __restrict__ Phi, unsigned short* __restrict__ Plo)
{
    const int kc = blockIdx.x;   // 0..23
    const int nb = blockIdx.y;   // 0..79
    const int l  = threadIdx.x;  // 0..63
    const int g = l >> 4, c = l & 15;
    const float* W; int N, nbl;
    if (nb < 32)      { W = Wsw;  N = 500; nbl = nb; }
    else if (nb < 64) { W = Wmem; N = 500; nbl = nb - 32; }
    else              { W = Wsv;  N = 250; nbl = nb - 64; }
    const int n = nbl * 16 + c;
    unsigned short h8[8], l8[8];
    #pragma unroll
    for (int j = 0; j < 8; ++j) {
        const int k = kc * 32 + g * 8 + j;
        const float w = (k < 750 && n < N) ? W[(size_t)k * N + n] : 0.f;
        const unsigned short h = f2bf(w);
        h8[j] = h;
        l8[j] = f2bf(w - bf2f(h));
    }
    const size_t off = ((size_t)nb * 24 + kc) * 512 + (size_t)l * 8;
    #pragma unroll
    for (int j = 0; j < 8; ++j) { Phi[off + j] = h8[j]; Plo[off + j] = l8[j]; }
}

// ---------------- persistent recurrence: all 24*6 layers in one kernel ----------------
// 48 blocks x 1024 threads (16 waves = 4/SIMD for latency hiding). Block = (rt, cg):
// rt = bid/3 owns rows rt*32..+31 (A staged once into 96KB swizzled LDS, 3x redundancy).
// cg = bid%3 owns 16 column-units; wave w -> one 16-col unit: pair (sw j + mem j, gating
// epilogue wave-local) or sv. Balanced: cg work = {27,27,26} half-GEMMs.
// Cross-block state via relaxed agent-scope atomics (@MALL); no cache fences => weights
// stay cache-resident across steps. Grid barrier: RMW-arrive counter + read-only release.
__launch_bounds__(1024)
__global__ void recurrence(RecArgs A)
{
    __shared__ __align__(16) unsigned char lds[98304];   // [plane 0=hi,1=lo][row 0..31][1536B, XOR-swizzled]
    const int tid = threadIdx.x;
    const int bid = blockIdx.x;
    const int w  = tid >> 6;        // wave 0..15
    const int l6 = tid & 63;
    const int g = l6 >> 4, c = l6 & 15;
    const int asw = (c & 7) << 4;   // FRAG XOR bits (row&7 == c&7 since rb*16 % 8 == 0)

    const int rt = bid / 3, cg = bid - 3 * rt;
    const int m0 = rt * 32;

    const int npair = (cg == 2) ? 10 : 11;
    const int pbase = cg * 11;      // 0,11,22
    const int sbase = cg * 5;       // 0,5,10
    const bool ispair = (w < npair);
    const int u = ispair ? (pbase + w) : (sbase + (w - npair));
    const int col = u * 16 + c;     // pair: m-col 0..511 (valid<500); sv: x-col 0..255 (valid<250)

    const size_t lnoff = (size_t)l6 * 8;
    const size_t bofs0 = ((size_t)((ispair ? u : 64 + u) * 24)) * 512 + lnoff;
    const size_t bofs1 = ((size_t)((32 + u) * 24)) * 512 + lnoff;    // pair only

    float mreg[2][4];
    #pragma unroll
    for (int i = 0; i < 2; ++i)
        #pragma unroll
        for (int j = 0; j < 4; ++j) mreg[i][j] = 0.f;

#define FRAG(p, rb, kc) (*(const bf16x8*)(lds + (p) * 49152 + ((rb) * 16 + c) * 1536 + ((((kc) * 64) + g * 16) ^ asw)))

    #pragma unroll 1
    for (int step = 0; step < NSTEP; ++step) {
        const int t = step / 6;
        const int l = step - 6 * t;
        const unsigned short* Ahi = (step & 1) ? A.A1hi : A.A0hi;
        const unsigned short* Alo = (step & 1) ? A.A1lo : A.A0lo;
        unsigned short* Ohi = (step & 1) ? A.A0hi : A.A1hi;
        unsigned short* Olo = (step & 1) ? A.A0lo : A.A1lo;
        const unsigned short* Phi = A.Pw + (size_t)l * 2 * PL;
        const unsigned short* Plo = Phi + PL;

        // ---- stage A rows [m0, m0+32), hi+lo, into swizzled LDS (coalesced 8B agent loads) ----
        // 32 rows x 192 chunks x 8B per plane = 6144 chunks; BOTH planes loaded per iter
        // => 6144 / 1024 threads = 6 iterations.  (Round-4 bug: 12 iters overran LDS.)
        {
            const unsigned long long* sh = (const unsigned long long*)(Ahi + (size_t)m0 * SS);
            const unsigned long long* sl = (const unsigned long long*)(Alo + (size_t)m0 * SS);
            #pragma unroll
            for (int j = 0; j < 6; ++j) {
                const int f = tid + j * 1024;         // 8B chunk id, 0..6143 (= row*192 + ko/8)
                const int row = f / 192;
                const int ko = (f - row * 192) * 8;   // byte offset within row
                const int d = row * 1536 + (ko ^ ((row & 7) << 4));
                const unsigned long long vh = __hip_atomic_load(sh + f, __ATOMIC_RELAXED, __HIP_MEMORY_SCOPE_AGENT);
                const unsigned long long vl = __hip_atomic_load(sl + f, __ATOMIC_RELAXED, __HIP_MEMORY_SCOPE_AGENT);
                *(unsigned long long*)(lds + d) = vh;
                *(unsigned long long*)(lds + 49152 + d) = vl;
            }
        }
        __syncthreads();

        if (ispair) {
            f32x4 z0[2], z1[2];
            z0[0] = (f32x4)0.f; z0[1] = (f32x4)0.f;
            z1[0] = (f32x4)0.f; z1[1] = (f32x4)0.f;
            #pragma unroll 2
            for (int kc = 0; kc < 24; ++kc) {
                const bf16x8 ah0 = FRAG(0, 0, kc), ah1 = FRAG(0, 1, kc);
                const bf16x8 al0 = FRAG(1, 0, kc), al1 = FRAG(1, 1, kc);
                const size_t k5 = (size_t)kc * 512;
                const bf16x8 bh0 = LD8(Phi + bofs0 + k5);
                const bf16x8 bl0 = LD8(Plo + bofs0 + k5);
                const bf16x8 bh1 = LD8(Phi + bofs1 + k5);
                const bf16x8 bl1 = LD8(Plo + bofs1 + k5);
                z0[0] = mm(ah0, bh0, z0[0]); z0[0] = mm(al0, bh0, z0[0]); z0[0] = mm(ah0, bl0, z0[0]);
                z0[1] = mm(ah1, bh0, z0[1]); z0[1] = mm(al1, bh0, z0[1]); z0[1] = mm(ah1, bl0, z0[1]);
                z1[0] = mm(ah0, bh1, z1[0]); z1[0] = mm(al0, bh1, z1[0]); z1[0] = mm(ah0, bl1, z1[0]);
                z1[1] = mm(ah1, bh1, z1[1]); z1[1] = mm(al1, bh1, z1[1]); z1[1] = mm(ah1, bl1, z1[1]);
            }
            if (col < 500) {
                const float* bswp  = l ? A.b_sw  + (size_t)(l - 1) * 500 : A.b1_sw;
                const float* bmemp = l ? A.b_mem + (size_t)(l - 1) * 500 : A.b1_mem;
                const float bs = bswp[col];
                const float bm = bmemp[col];
                #pragma unroll
                for (int rb = 0; rb < 2; ++rb) {
                    #pragma unroll
                    for (int r = 0; r < 4; ++r) {
                        const int row = m0 + rb * 16 + g * 4 + r;
                        float zs = z0[rb][r] + bs;
                        float zm = z1[rb][r] + bm;
                        if (l == 0) {
                            const int lt = A.letters[row * NT + t];
                            zs += A.w1_sw[(size_t)(750 + lt) * 500 + col];
                            zm += A.w1_mem[(size_t)(750 + lt) * 500 + col];
                        }
                        const float s = 1.f / (1.f + expf(-zs));
                        const float mn = mreg[rb][r] * s + tanhf(zm) * (1.f - s);
                        mreg[rb][r] = mn;
                        const size_t o = (size_t)row * SS + 250 + col;
                        const unsigned short h = f2bf(mn);
                        const unsigned short lo2 = f2bf(mn - bf2f(h));
                        __hip_atomic_store(Ohi + o, h, __ATOMIC_RELAXED, __HIP_MEMORY_SCOPE_AGENT);
                        __hip_atomic_store(Olo + o, lo2, __ATOMIC_RELAXED, __HIP_MEMORY_SCOPE_AGENT);
                        if (step == NSTEP - 1) A.Sfin[o] = mn;
                    }
                }
            }
        } else {
            f32x4 z0[2];
            z0[0] = (f32x4)0.f; z0[1] = (f32x4)0.f;
            #pragma unroll 2
            for (int kc = 0; kc < 24; ++kc) {
                const bf16x8 ah0 = FRAG(0, 0, kc), ah1 = FRAG(0, 1, kc);
                const bf16x8 al0 = FRAG(1, 0, kc), al1 = FRAG(1, 1, kc);
                const size_t k5 = (size_t)kc * 512;
                const bf16x8 bh = LD8(Phi + bofs0 + k5);
                const bf16x8 bl = LD8(Plo + bofs0 + k5);
                z0[0] = mm(ah0, bh, z0[0]); z0[0] = mm(al0, bh, z0[0]); z0[0] = mm(ah0, bl, z0[0]);
                z0[1] = mm(ah1, bh, z0[1]); z0[1] = mm(al1, bh, z0[1]); z0[1] = mm(ah1, bl, z0[1]);
            }
            if (col < 250) {
                const float* bsvp = l ? A.b_sv + (size_t)(l - 1) * 250 : A.b1_sv;
                const float bv = bsvp[col];
                #pragma unroll
                for (int rb = 0; rb < 2; ++rb) {
                    #pragma unroll
                    for (int r = 0; r < 4; ++r) {
                        const int row = m0 + rb * 16 + g * 4 + r;
                        float z = z0[rb][r] + bv;
                        if (l == 0) {
                            const int lt = A.letters[row * NT + t];
                            z += A.w1_sv[(size_t)(750 + lt) * 250 + col];
                        }
                        const float x = tanhf(z);
                        const size_t o = (size_t)row * SS + col;
                        const unsigned short h = f2bf(x);
                        const unsigned short lo2 = f2bf(x - bf2f(h));
                        __hip_atomic_store(Ohi + o, h, __ATOMIC_RELAXED, __HIP_MEMORY_SCOPE_AGENT);
                        __hip_atomic_store(Olo + o, lo2, __ATOMIC_RELAXED, __HIP_MEMORY_SCOPE_AGENT);
                        if (step == NSTEP - 1) A.Sfin[o] = x;
                    }
                }
            }
        }

        // ---- grid barrier: RMW arrivals on cnt, spin on read-only release word ----
        __syncthreads();                         // drains vmcnt: this block's sc1 stores visible @ MALL
        if (step != NSTEP - 1) {
            if (tid == 0) {
                const unsigned v = __hip_atomic_fetch_add(A.cnt, 1u, __ATOMIC_RELAXED, __HIP_MEMORY_SCOPE_AGENT);
                if (v == (unsigned)(NBLK * (step + 1)) - 1u) {
                    __hip_atomic_store(A.rel, (unsigned)(step + 1), __ATOMIC_RELAXED, __HIP_MEMORY_SCOPE_AGENT);
                } else {
                    while (__hip_atomic_load(A.rel, __ATOMIC_RELAXED, __HIP_MEMORY_SCOPE_AGENT) < (unsigned)(step + 1))
                        __builtin_amdgcn_s_sleep(2);
                }
            }
            __syncthreads();
        }
    }
#undef FRAG
}

// ---------------- head GEMM: Y = tanh(X @ W + b) (fp32) ----------------
__launch_bounds__(128)
__global__ void head_gemm(const float* __restrict__ X, int ldx, int K,
                          const float* __restrict__ W, const float* __restrict__ bias,
                          float* __restrict__ Y, int N)
{
    const int tid = threadIdx.x;
    const int m0 = blockIdx.y * 32;
    const int n0 = blockIdx.x * 64;

    __shared__ float As[2][32][36];
    __shared__ float Bs[2][32][68];

    const int tx = tid & 15, ty = tid >> 4;
    const int kl = tid & 31, rl = tid >> 5;
    const int cl = tid & 63, kg = tid >> 6;
    const bool cok = (n0 + cl) < N;

    float acc[4][4] = {{0.f}};
    float ar[8], br[16];

    {
        const float* a = X + (size_t)(m0 + rl) * ldx + kl;
        #pragma unroll
        for (int i = 0; i < 8; i++) ar[i] = a[(size_t)(4 * i) * ldx];
        #pragma unroll
        for (int i = 0; i < 16; i++)
            br[i] = cok ? W[(size_t)(kg + 2 * i) * N + n0 + cl] : 0.f;
        #pragma unroll
        for (int i = 0; i < 8; i++) As[0][kl][rl + 4 * i] = ar[i];
        #pragma unroll
        for (int i = 0; i < 16; i++) Bs[0][kg + 2 * i][cl] = br[i];
    }
    __syncthreads();

    int buf = 0;
    const int NK = (K + 31) / 32;
    #pragma unroll 1
    for (int kt = 0; kt < NK; kt++) {
        const bool more = (kt + 1 < NK);
        if (more) {
            const int k0 = (kt + 1) * 32;
            const bool ka = (k0 + kl) < K;
            const float* a = X + (size_t)(m0 + rl) * ldx + k0 + kl;
            #pragma unroll
            for (int i = 0; i < 8; i++) ar[i] = ka ? a[(size_t)(4 * i) * ldx] : 0.f;
            #pragma unroll
            for (int i = 0; i < 16; i++) {
                const int kk = k0 + kg + 2 * i;
                br[i] = (cok && kk < K) ? W[(size_t)kk * N + n0 + cl] : 0.f;
            }
        }
        #pragma unroll
        for (int kk = 0; kk < 32; kk++) {
            float4 av = *(const float4*)&As[buf][kk][ty * 4];
            float4 bv = *(const float4*)&Bs[buf][kk][tx * 4];
            const float aa[4] = {av.x, av.y, av.z, av.w};
            const float bb[4] = {bv.x, bv.y, bv.z, bv.w};
            #pragma unroll
            for (int i = 0; i < 4; i++)
                #pragma unroll
                for (int j = 0; j < 4; j++)
                    acc[i][j] = fmaf(aa[i], bb[j], acc[i][j]);
        }
        if (more) {
            #pragma unroll
            for (int i = 0; i < 8; i++) As[buf ^ 1][kl][rl + 4 * i] = ar[i];
            #pragma unroll
            for (int i = 0; i < 16; i++) Bs[buf ^ 1][kg + 2 * i][cl] = br[i];
            __syncthreads();
            buf ^= 1;
        }
    }

    #pragma unroll
    for (int i = 0; i < 4; i++) {
        const int b = m0 + ty * 4 + i;
        #pragma unroll
        for (int j = 0; j < 4; j++) {
            const int n = n0 + tx * 4 + j;
            if (n < N) Y[(size_t)b * N + n] = tanhf(acc[i][j] + bias[n]);
        }
    }
}

// ---------------- final: logits (K=100, N=30) + softmax ----------------
__global__ void head_final(const float* __restrict__ Y4, const float* __restrict__ W,
                           const float* __restrict__ bias, float* __restrict__ out)
{
    const int row = blockIdx.x;
    __shared__ float y[100];
    __shared__ float z[NV];
    for (int k = threadIdx.x; k < 100; k += 64) y[k] = Y4[row * 100 + k];
    __syncthreads();
    const int n = threadIdx.x;
    if (n < NV) {
        float acc = bias[n];
        for (int k = 0; k < 100; k++) acc = fmaf(y[k], W[k * NV + n], acc);
        z[n] = acc;
    }
    __syncthreads();
    if (n < NV) {
        float mx = -1e30f;
        for (int i = 0; i < NV; i++) mx = fmaxf(mx, z[i]);
        float sum = 0.f;
        for (int i = 0; i < NV; i++) sum += expf(z[i] - mx);
        out[row * NV + n] = expf(z[n] - mx) / sum;
    }
}

extern "C" void kernel_launch(void* const* d_in, const int* in_sizes, int n_in,
                              void* d_out, int out_size, void* d_ws, size_t ws_size,
                              hipStream_t stream)
{
    const int*   letters = (const int*)  d_in[0];
    const float* w1_sv   = (const float*)d_in[1];
    const float* b1_sv   = (const float*)d_in[2];
    const float* w1_mem  = (const float*)d_in[3];
    const float* b1_mem  = (const float*)d_in[4];
    const float* w1_sw   = (const float*)d_in[5];
    const float* b1_sw   = (const float*)d_in[6];
    const float* w_sv    = (const float*)d_in[7];
    const float* b_sv    = (const float*)d_in[8];
    const float* w_mem   = (const float*)d_in[9];
    const float* b_mem   = (const float*)d_in[10];
    const float* w_sw    = (const float*)d_in[11];
    const float* b_sw    = (const float*)d_in[12];
    const float* wp1 = (const float*)d_in[13]; const float* bp1 = (const float*)d_in[14];
    const float* wp2 = (const float*)d_in[15]; const float* bp2 = (const float*)d_in[16];
    const float* wp3 = (const float*)d_in[17]; const float* bp3 = (const float*)d_in[18];
    const float* wp4 = (const float*)d_in[19]; const float* bp4 = (const float*)d_in[20];
    const float* wp5 = (const float*)d_in[21]; const float* bp5 = (const float*)d_in[22];

    // workspace layout
    float* Sfin = (float*)d_ws;                                   // BSZ*SS f32 (written at final step)
    float* cntf = Sfin + (size_t)BSZ * SS;                        // 64 f32: cnt line + rel line
    unsigned int* cnt = (unsigned int*)cntf;
    unsigned int* rel = cnt + 32;                                 // separate 128B line
    unsigned short* A0hi = (unsigned short*)(cntf + 64);
    unsigned short* A0lo = A0hi + (size_t)BSZ * SS;
    unsigned short* A1hi = A0lo + (size_t)BSZ * SS;
    unsigned short* A1lo = A1hi + (size_t)BSZ * SS;
    unsigned short* Pw   = A1lo + (size_t)BSZ * SS;               // 12 * PL ushorts
    float* Y1 = (float*)(Pw + (size_t)12 * PL);
    float* Y2 = Y1 + (size_t)BSZ * 450;
    float* Y3 = Y2 + (size_t)BSZ * 300;
    float* Y4 = Y3 + (size_t)BSZ * 200;

    // zero barrier words + all 4 bf16 state planes (incl. K-pad cols, which stay 0 forever)
    zero_kernel<<<512, 256, 0, stream>>>(cntf, 64 + 2 * BSZ * SS);

    // one-time weight packing
    pack_weights<<<dim3(24, 80), 64, 0, stream>>>(w1_sw, w1_mem, w1_sv, Pw, Pw + PL);
    for (int l = 1; l < 6; ++l)
        pack_weights<<<dim3(24, 80), 64, 0, stream>>>(
            w_sw  + (size_t)(l - 1) * 750 * 500,
            w_mem + (size_t)(l - 1) * 750 * 500,
            w_sv  + (size_t)(l - 1) * 750 * 250,
            Pw + (size_t)l * 2 * PL, Pw + (size_t)l * 2 * PL + PL);

    RecArgs ra;
    ra.Pw = Pw;
    ra.A0hi = A0hi; ra.A0lo = A0lo; ra.A1hi = A1hi; ra.A1lo = A1lo;
    ra.Sfin = Sfin; ra.cnt = cnt; ra.rel = rel;
    ra.b1_sw = b1_sw; ra.b1_mem = b1_mem; ra.b1_sv = b1_sv;
    ra.b_sw = b_sw;   ra.b_mem = b_mem;   ra.b_sv = b_sv;
    ra.w1_sw = w1_sw; ra.w1_mem = w1_mem; ra.w1_sv = w1_sv;
    ra.letters = letters;
    recurrence<<<NBLK, 1024, 0, stream>>>(ra);

    head_gemm<<<dim3(8, 16), 128, 0, stream>>>(Sfin, SS, 750, wp1, bp1, Y1, 450);
    head_gemm<<<dim3(5, 16), 128, 0, stream>>>(Y1, 450, 450, wp2, bp2, Y2, 300);
    head_gemm<<<dim3(4, 16), 128, 0, stream>>>(Y2, 300, 300, wp3, bp3, Y3, 200);
    head_gemm<<<dim3(2, 16), 128, 0, stream>>>(Y3, 200, 200, wp4, bp4, Y4, 100);
    head_final<<<BSZ, 64, 0, stream>>>(Y4, wp5, bp5, (float*)d_out);
}

// Round 6
// 3086.948 us; speedup vs baseline: 1.1910x; 1.1607x over previous
//
#include <hip/hip_runtime.h>
#include <math.h>

#define BSZ 512
#define NV 30
#define NT 24
#define SS 768                  // state row stride (x: 0..249, m: 250..749, pad: 750..767)
#define PL (80 * 24 * 512)      // packed ushorts per (layer, half): 80 nb-blocks x 24 kc x 512
#define NBLK 128
#define NSTEP 144

typedef __attribute__((ext_vector_type(8))) short bf16x8;
typedef __attribute__((ext_vector_type(4))) float f32x4;

__device__ __forceinline__ unsigned short f2bf(float f) {
    unsigned u = __float_as_uint(f);
    u += 0x7fffu + ((u >> 16) & 1u);        // round-to-nearest-even
    return (unsigned short)(u >> 16);
}
__device__ __forceinline__ float bf2f(unsigned short h) {
    return __uint_as_float(((unsigned)h) << 16);
}
__device__ __forceinline__ f32x4 mm(bf16x8 a, bf16x8 b, f32x4 c) {
    return __builtin_amdgcn_mfma_f32_16x16x32_bf16(a, b, c, 0, 0, 0);
}
#define LD8(p) (*(const bf16x8*)(const void*)(p))

struct RecArgs {
    const unsigned short* Pw;
    unsigned short* A0hi; unsigned short* A0lo;
    unsigned short* A1hi; unsigned short* A1lo;
    float* Sfin;
    unsigned int* cnt; unsigned int* rel;
    const float* b1_sw; const float* b1_mem; const float* b1_sv;
    const float* b_sw;  const float* b_mem;  const float* b_sv;
    const float* w1_sw; const float* w1_mem; const float* w1_sv;
    const int* letters;
};

// ---------------- zero ----------------
__global__ void zero_kernel(float* p, int n) {
    int i = blockIdx.x * blockDim.x + threadIdx.x;
    int st = gridDim.x * blockDim.x;
    for (; i < n; i += st) p[i] = 0.f;
}

// ---------------- one-time weight pack: fp32 [750][N] -> hi/lo bf16 MFMA-B layout ----------------
// Phi[((nb*24 + kc)*64 + lane)*8 + j] = bf16_hi(W[kc*32 + (lane>>4)*8 + j][nb*16 + (lane&15)])
// nb 0..31 = sw (N=500 pad 512), 32..63 = mem, 64..79 = sv (N=250 pad 256). k>=750 zero-padded.
__launch_bounds__(64)
__global__ void pack_weights(const float* __restrict__ Wsw, const float* __restrict__ Wmem,
                             const float* __restrict__ Wsv,
                             unsigned short* __restrict__ Phi, unsigned short* __restrict__ Plo)
{
    const int kc = blockIdx.x;   // 0..23
    const int nb = blockIdx.y;   // 0..79
    const int l  = threadIdx.x;  // 0..63
    const int g = l >> 4, c = l & 15;
    const float* W; int N, nbl;
    if (nb < 32)      { W = Wsw;  N = 500; nbl = nb; }
    else if (nb < 64) { W = Wmem; N = 500; nbl = nb - 32; }
    else              { W = Wsv;  N = 250; nbl = nb - 64; }
    const int n = nbl * 16 + c;
    unsigned short h8[8], l8[8];
    #pragma unroll
    for (int j = 0; j < 8; ++j) {
        const int k = kc * 32 + g * 8 + j;
        const float w = (k < 750 && n < N) ? W[(size_t)k * N + n] : 0.f;
        const unsigned short h = f2bf(w);
        h8[j] = h;
        l8[j] = f2bf(w - bf2f(h));
    }
    const size_t off = ((size_t)nb * 24 + kc) * 512 + (size_t)l * 8;
    #pragma unroll
    for (int j = 0; j < 8; ++j) { Phi[off + j] = h8[j]; Plo[off + j] = l8[j]; }
}

// ---------------- persistent recurrence: all 24*6 layers in one kernel ----------------
// 128 blocks x 384 threads (6 waves). Weight-stationary XCD partition:
//   cx = bid & 7  -> XCD under round-robin workgroup dispatch (%8 heuristic).
//   Column-group cx owns sw units 4cx..4cx+3 (+paired mem) and sv units 2cx,2cx+1
//   for ALL 6 layers => per-XCD weight footprint = 23.6MB/8 = 2.95MB < 4MB L2.
//   After the first 6 steps every B load is an L2 hit (~200cy) instead of a MALL
//   miss (~800cy) -- round-5 counters showed B-misses (17.8MB/step FETCH) were the
//   structural bottleneck. If the %8 mapping assumption is wrong this degrades to
//   round-5 behavior (flat), never worse.
//   rg = bid >> 3 -> rows rg*32..+31 (A staged to 96KB swizzled LDS).
// Waves 0..3 = pair (sw j + mem j, gating epilogue wave-local, m carried in regs);
// waves 4..5 = sv. Cross-block state via relaxed agent-scope atomics (@MALL);
// grid barrier: RMW-arrive counter + read-only release word (verified by absmax canary).
__launch_bounds__(384, 1)
__global__ void recurrence(RecArgs A)
{
    __shared__ __align__(16) unsigned char lds[98304];   // [plane 0=hi,1=lo][row 0..31][1536B, XOR-swizzled]
    const int tid = threadIdx.x;
    const int bid = blockIdx.x;
    const int w  = tid >> 6;        // wave 0..5
    const int l6 = tid & 63;
    const int g = l6 >> 4, c = l6 & 15;
    const int asw = (c & 7) << 4;   // FRAG XOR bits (row&7 == c&7 since rb*16 % 8 == 0)

    const int cx = bid & 7;         // column-group == XCD (under %8 round-robin)
    const int rg = bid >> 3;        // 0..15
    const int m0 = rg * 32;

    const bool ispair = (w < 4);
    const int u = ispair ? (4 * cx + w) : (2 * cx + (w - 4));
    const int col = u * 16 + c;     // pair: m-col 0..511 (valid<500); sv: x-col 0..255 (valid<250)

    const size_t lnoff = (size_t)l6 * 8;
    const size_t bofs0 = ((size_t)((ispair ? u : 64 + u) * 24)) * 512 + lnoff;
    const size_t bofs1 = ((size_t)((32 + u) * 24)) * 512 + lnoff;    // pair only

    float mreg[2][4];
    #pragma unroll
    for (int i = 0; i < 2; ++i)
        #pragma unroll
        for (int j = 0; j < 4; ++j) mreg[i][j] = 0.f;

#define FRAG(p, rb, kc) (*(const bf16x8*)(lds + (p) * 49152 + ((rb) * 16 + c) * 1536 + ((((kc) * 64) + g * 16) ^ asw)))

    #pragma unroll 1
    for (int step = 0; step < NSTEP; ++step) {
        const int t = step / 6;
        const int l = step - 6 * t;
        const unsigned short* Ahi = (step & 1) ? A.A1hi : A.A0hi;
        const unsigned short* Alo = (step & 1) ? A.A1lo : A.A0lo;
        unsigned short* Ohi = (step & 1) ? A.A0hi : A.A1hi;
        unsigned short* Olo = (step & 1) ? A.A0lo : A.A1lo;
        const unsigned short* Phi = A.Pw + (size_t)l * 2 * PL;
        const unsigned short* Plo = Phi + PL;

        // ---- stage A rows [m0, m0+32), hi+lo, into swizzled LDS (coalesced 8B agent loads) ----
        // 32 rows x 192 chunks x 8B per plane = 6144 chunks; both planes per iter
        // => 6144 / 384 threads = 16 iterations (all loads independent, latency-tolerant).
        {
            const unsigned long long* sh = (const unsigned long long*)(Ahi + (size_t)m0 * SS);
            const unsigned long long* sl = (const unsigned long long*)(Alo + (size_t)m0 * SS);
            #pragma unroll
            for (int j = 0; j < 16; ++j) {
                const int f = tid + j * 384;          // 8B chunk id, 0..6143 (= row*192 + ko/8)
                const int row = f / 192;
                const int ko = (f - row * 192) * 8;   // byte offset within row
                const int d = row * 1536 + (ko ^ ((row & 7) << 4));
                const unsigned long long vh = __hip_atomic_load(sh + f, __ATOMIC_RELAXED, __HIP_MEMORY_SCOPE_AGENT);
                const unsigned long long vl = __hip_atomic_load(sl + f, __ATOMIC_RELAXED, __HIP_MEMORY_SCOPE_AGENT);
                *(unsigned long long*)(lds + d) = vh;
                *(unsigned long long*)(lds + 49152 + d) = vl;
            }
        }
        __syncthreads();

        if (ispair) {
            f32x4 z0[2], z1[2];
            z0[0] = (f32x4)0.f; z0[1] = (f32x4)0.f;
            z1[0] = (f32x4)0.f; z1[1] = (f32x4)0.f;
            #pragma unroll 4
            for (int kc = 0; kc < 24; ++kc) {
                const bf16x8 ah0 = FRAG(0, 0, kc), ah1 = FRAG(0, 1, kc);
                const bf16x8 al0 = FRAG(1, 0, kc), al1 = FRAG(1, 1, kc);
                const size_t k5 = (size_t)kc * 512;
                const bf16x8 bh0 = LD8(Phi + bofs0 + k5);
                const bf16x8 bl0 = LD8(Plo + bofs0 + k5);
                const bf16x8 bh1 = LD8(Phi + bofs1 + k5);
                const bf16x8 bl1 = LD8(Plo + bofs1 + k5);
                z0[0] = mm(ah0, bh0, z0[0]); z0[0] = mm(al0, bh0, z0[0]); z0[0] = mm(ah0, bl0, z0[0]);
                z0[1] = mm(ah1, bh0, z0[1]); z0[1] = mm(al1, bh0, z0[1]); z0[1] = mm(ah1, bl0, z0[1]);
                z1[0] = mm(ah0, bh1, z1[0]); z1[0] = mm(al0, bh1, z1[0]); z1[0] = mm(ah0, bl1, z1[0]);
                z1[1] = mm(ah1, bh1, z1[1]); z1[1] = mm(al1, bh1, z1[1]); z1[1] = mm(ah1, bl1, z1[1]);
            }
            if (col < 500) {
                const float* bswp  = l ? A.b_sw  + (size_t)(l - 1) * 500 : A.b1_sw;
                const float* bmemp = l ? A.b_mem + (size_t)(l - 1) * 500 : A.b1_mem;
                const float bs = bswp[col];
                const float bm = bmemp[col];
                #pragma unroll
                for (int rb = 0; rb < 2; ++rb) {
                    #pragma unroll
                    for (int r = 0; r < 4; ++r) {
                        const int row = m0 + rb * 16 + g * 4 + r;
                        float zs = z0[rb][r] + bs;
                        float zm = z1[rb][r] + bm;
                        if (l == 0) {
                            const int lt = A.letters[row * NT + t];
                            zs += A.w1_sw[(size_t)(750 + lt) * 500 + col];
                            zm += A.w1_mem[(size_t)(750 + lt) * 500 + col];
                        }
                        const float s = 1.f / (1.f + expf(-zs));
                        const float mn = mreg[rb][r] * s + tanhf(zm) * (1.f - s);
                        mreg[rb][r] = mn;
                        const size_t o = (size_t)row * SS + 250 + col;
                        const unsigned short h = f2bf(mn);
                        const unsigned short lo2 = f2bf(mn - bf2f(h));
                        __hip_atomic_store(Ohi + o, h, __ATOMIC_RELAXED, __HIP_MEMORY_SCOPE_AGENT);
                        __hip_atomic_store(Olo + o, lo2, __ATOMIC_RELAXED, __HIP_MEMORY_SCOPE_AGENT);
                        if (step == NSTEP - 1) A.Sfin[o] = mn;
                    }
                }
            }
        } else {
            f32x4 z0[2];
            z0[0] = (f32x4)0.f; z0[1] = (f32x4)0.f;
            #pragma unroll 4
            for (int kc = 0; kc < 24; ++kc) {
                const bf16x8 ah0 = FRAG(0, 0, kc), ah1 = FRAG(0, 1, kc);
                const bf16x8 al0 = FRAG(1, 0, kc), al1 = FRAG(1, 1, kc);
                const size_t k5 = (size_t)kc * 512;
                const bf16x8 bh = LD8(Phi + bofs0 + k5);
                const bf16x8 bl = LD8(Plo + bofs0 + k5);
                z0[0] = mm(ah0, bh, z0[0]); z0[0] = mm(al0, bh, z0[0]); z0[0] = mm(ah0, bl, z0[0]);
                z0[1] = mm(ah1, bh, z0[1]); z0[1] = mm(al1, bh, z0[1]); z0[1] = mm(ah1, bl, z0[1]);
            }
            if (col < 250) {
                const float* bsvp = l ? A.b_sv + (size_t)(l - 1) * 250 : A.b1_sv;
                const float bv = bsvp[col];
                #pragma unroll
                for (int rb = 0; rb < 2; ++rb) {
                    #pragma unroll
                    for (int r = 0; r < 4; ++r) {
                        const int row = m0 + rb * 16 + g * 4 + r;
                        float z = z0[rb][r] + bv;
                        if (l == 0) {
                            const int lt = A.letters[row * NT + t];
                            z += A.w1_sv[(size_t)(750 + lt) * 250 + col];
                        }
                        const float x = tanhf(z);
                        const size_t o = (size_t)row * SS + col;
                        const unsigned short h = f2bf(x);
                        const unsigned short lo2 = f2bf(x - bf2f(h));
                        __hip_atomic_store(Ohi + o, h, __ATOMIC_RELAXED, __HIP_MEMORY_SCOPE_AGENT);
                        __hip_atomic_store(Olo + o, lo2, __ATOMIC_RELAXED, __HIP_MEMORY_SCOPE_AGENT);
                        if (step == NSTEP - 1) A.Sfin[o] = x;
                    }
                }
            }
        }

        // ---- grid barrier: RMW arrivals on cnt, spin on read-only release word ----
        __syncthreads();                         // drains vmcnt: this block's sc1 stores visible @ MALL
        if (step != NSTEP - 1) {
            if (tid == 0) {
                const unsigned v = __hip_atomic_fetch_add(A.cnt, 1u, __ATOMIC_RELAXED, __HIP_MEMORY_SCOPE_AGENT);
                if (v == (unsigned)(NBLK * (step + 1)) - 1u) {
                    __hip_atomic_store(A.rel, (unsigned)(step + 1), __ATOMIC_RELAXED, __HIP_MEMORY_SCOPE_AGENT);
                } else {
                    while (__hip_atomic_load(A.rel, __ATOMIC_RELAXED, __HIP_MEMORY_SCOPE_AGENT) < (unsigned)(step + 1))
                        __builtin_amdgcn_s_sleep(2);
                }
            }
            __syncthreads();
        }
    }
#undef FRAG
}

// ---------------- head GEMM: Y = tanh(X @ W + b) (fp32) ----------------
__launch_bounds__(128)
__global__ void head_gemm(const float* __restrict__ X, int ldx, int K,
                          const float* __restrict__ W, const float* __restrict__ bias,
                          float* __restrict__ Y, int N)
{
    const int tid = threadIdx.x;
    const int m0 = blockIdx.y * 32;
    const int n0 = blockIdx.x * 64;

    __shared__ float As[2][32][36];
    __shared__ float Bs[2][32][68];

    const int tx = tid & 15, ty = tid >> 4;
    const int kl = tid & 31, rl = tid >> 5;
    const int cl = tid & 63, kg = tid >> 6;
    const bool cok = (n0 + cl) < N;

    float acc[4][4] = {{0.f}};
    float ar[8], br[16];

    {
        const float* a = X + (size_t)(m0 + rl) * ldx + kl;
        #pragma unroll
        for (int i = 0; i < 8; i++) ar[i] = a[(size_t)(4 * i) * ldx];
        #pragma unroll
        for (int i = 0; i < 16; i++)
            br[i] = cok ? W[(size_t)(kg + 2 * i) * N + n0 + cl] : 0.f;
        #pragma unroll
        for (int i = 0; i < 8; i++) As[0][kl][rl + 4 * i] = ar[i];
        #pragma unroll
        for (int i = 0; i < 16; i++) Bs[0][kg + 2 * i][cl] = br[i];
    }
    __syncthreads();

    int buf = 0;
    const int NK = (K + 31) / 32;
    #pragma unroll 1
    for (int kt = 0; kt < NK; kt++) {
        const bool more = (kt + 1 < NK);
        if (more) {
            const int k0 = (kt + 1) * 32;
            const bool ka = (k0 + kl) < K;
            const float* a = X + (size_t)(m0 + rl) * ldx + k0 + kl;
            #pragma unroll
            for (int i = 0; i < 8; i++) ar[i] = ka ? a[(size_t)(4 * i) * ldx] : 0.f;
            #pragma unroll
            for (int i = 0; i < 16; i++) {
                const int kk = k0 + kg + 2 * i;
                br[i] = (cok && kk < K) ? W[(size_t)kk * N + n0 + cl] : 0.f;
            }
        }
        #pragma unroll
        for (int kk = 0; kk < 32; kk++) {
            float4 av = *(const float4*)&As[buf][kk][ty * 4];
            float4 bv = *(const float4*)&Bs[buf][kk][tx * 4];
            const float aa[4] = {av.x, av.y, av.z, av.w};
            const float bb[4] = {bv.x, bv.y, bv.z, bv.w};
            #pragma unroll
            for (int i = 0; i < 4; i++)
                #pragma unroll
                for (int j = 0; j < 4; j++)
                    acc[i][j] = fmaf(aa[i], bb[j], acc[i][j]);
        }
        if (more) {
            #pragma unroll
            for (int i = 0; i < 8; i++) As[buf ^ 1][kl][rl + 4 * i] = ar[i];
            #pragma unroll
            for (int i = 0; i < 16; i++) Bs[buf ^ 1][kg + 2 * i][cl] = br[i];
            __syncthreads();
            buf ^= 1;
        }
    }

    #pragma unroll
    for (int i = 0; i < 4; i++) {
        const int b = m0 + ty * 4 + i;
        #pragma unroll
        for (int j = 0; j < 4; j++) {
            const int n = n0 + tx * 4 + j;
            if (n < N) Y[(size_t)b * N + n] = tanhf(acc[i][j] + bias[n]);
        }
    }
}

// ---------------- final: logits (K=100, N=30) + softmax ----------------
__global__ void head_final(const float* __restrict__ Y4, const float* __restrict__ W,
                           const float* __restrict__ bias, float* __restrict__ out)
{
    const int row = blockIdx.x;
    __shared__ float y[100];
    __shared__ float z[NV];
    for (int k = threadIdx.x; k < 100; k += 64) y[k] = Y4[row * 100 + k];
    __syncthreads();
    const int n = threadIdx.x;
    if (n < NV) {
        float acc = bias[n];
        for (int k = 0; k < 100; k++) acc = fmaf(y[k], W[k * NV + n], acc);
        z[n] = acc;
    }
    __syncthreads();
    if (n < NV) {
        float mx = -1e30f;
        for (int i = 0; i < NV; i++) mx = fmaxf(mx, z[i]);
        float sum = 0.f;
        for (int i = 0; i < NV; i++) sum += expf(z[i] - mx);
        out[row * NV + n] = expf(z[n] - mx) / sum;
    }
}

extern "C" void kernel_launch(void* const* d_in, const int* in_sizes, int n_in,
                              void* d_out, int out_size, void* d_ws, size_t ws_size,
                              hipStream_t stream)
{
    const int*   letters = (const int*)  d_in[0];
    const float* w1_sv   = (const float*)d_in[1];
    const float* b1_sv   = (const float*)d_in[2];
    const float* w1_mem  = (const float*)d_in[3];
    const float* b1_mem  = (const float*)d_in[4];
    const float* w1_sw   = (const float*)d_in[5];
    const float* b1_sw   = (const float*)d_in[6];
    const float* w_sv    = (const float*)d_in[7];
    const float* b_sv    = (const float*)d_in[8];
    const float* w_mem   = (const float*)d_in[9];
    const float* b_mem   = (const float*)d_in[10];
    const float* w_sw    = (const float*)d_in[11];
    const float* b_sw    = (const float*)d_in[12];
    const float* wp1 = (const float*)d_in[13]; const float* bp1 = (const float*)d_in[14];
    const float* wp2 = (const float*)d_in[15]; const float* bp2 = (const float*)d_in[16];
    const float* wp3 = (const float*)d_in[17]; const float* bp3 = (const float*)d_in[18];
    const float* wp4 = (const float*)d_in[19]; const float* bp4 = (const float*)d_in[20];
    const float* wp5 = (const float*)d_in[21]; const float* bp5 = (const float*)d_in[22];

    // workspace layout
    float* Sfin = (float*)d_ws;                                   // BSZ*SS f32 (written at final step)
    float* cntf = Sfin + (size_t)BSZ * SS;                        // 64 f32: cnt line + rel line
    unsigned int* cnt = (unsigned int*)cntf;
    unsigned int* rel = cnt + 32;                                 // separate 128B line
    unsigned short* A0hi = (unsigned short*)(cntf + 64);
    unsigned short* A0lo = A0hi + (size_t)BSZ * SS;
    unsigned short* A1hi = A0lo + (size_t)BSZ * SS;
    unsigned short* A1lo = A1hi + (size_t)BSZ * SS;
    unsigned short* Pw   = A1lo + (size_t)BSZ * SS;               // 12 * PL ushorts
    float* Y1 = (float*)(Pw + (size_t)12 * PL);
    float* Y2 = Y1 + (size_t)BSZ * 450;
    float* Y3 = Y2 + (size_t)BSZ * 300;
    float* Y4 = Y3 + (size_t)BSZ * 200;

    // zero barrier words + all 4 bf16 state planes (incl. K-pad cols, which stay 0 forever)
    zero_kernel<<<512, 256, 0, stream>>>(cntf, 64 + 2 * BSZ * SS);

    // one-time weight packing
    pack_weights<<<dim3(24, 80), 64, 0, stream>>>(w1_sw, w1_mem, w1_sv, Pw, Pw + PL);
    for (int l = 1; l < 6; ++l)
        pack_weights<<<dim3(24, 80), 64, 0, stream>>>(
            w_sw  + (size_t)(l - 1) * 750 * 500,
            w_mem + (size_t)(l - 1) * 750 * 500,
            w_sv  + (size_t)(l - 1) * 750 * 250,
            Pw + (size_t)l * 2 * PL, Pw + (size_t)l * 2 * PL + PL);

    RecArgs ra;
    ra.Pw = Pw;
    ra.A0hi = A0hi; ra.A0lo = A0lo; ra.A1hi = A1hi; ra.A1lo = A1lo;
    ra.Sfin = Sfin; ra.cnt = cnt; ra.rel = rel;
    ra.b1_sw = b1_sw; ra.b1_mem = b1_mem; ra.b1_sv = b1_sv;
    ra.b_sw = b_sw;   ra.b_mem = b_mem;   ra.b_sv = b_sv;
    ra.w1_sw = w1_sw; ra.w1_mem = w1_mem; ra.w1_sv = w1_sv;
    ra.letters = letters;
    recurrence<<<NBLK, 384, 0, stream>>>(ra);

    head_gemm<<<dim3(8, 16), 128, 0, stream>>>(Sfin, SS, 750, wp1, bp1, Y1, 450);
    head_gemm<<<dim3(5, 16), 128, 0, stream>>>(Y1, 450, 450, wp2, bp2, Y2, 300);
    head_gemm<<<dim3(4, 16), 128, 0, stream>>>(Y2, 300, 300, wp3, bp3, Y3, 200);
    head_gemm<<<dim3(2, 16), 128, 0, stream>>>(Y3, 200, 200, wp4, bp4, Y4, 100);
    head_final<<<BSZ, 64, 0, stream>>>(Y4, wp5, bp5, (float*)d_out);
}